// Round 6
// baseline (865.682 us; speedup 1.0000x reference)
//
#include <hip/hip_runtime.h>

#define N_NODES 100000
#define N_EDGES 1600000
#define D_IN    128
#define D_OUT   64

#define XT_STRIDE 260     // gemm xT padded stride
#define NB    256         // binning blocks
#define CHUNK 6250        // edges per binning block (256*6250 = 1.6M exact)
#define NG    782         // buckets: row>>7, ceil(100000/128)
#define BROWS 128         // rows per bucket
typedef unsigned long long ull;

// ---------------------------------------------------------------------------
// Kernel A: support = X @ W (fp32). Register-tiled LDS GEMM (unchanged).
// ---------------------------------------------------------------------------
__global__ __launch_bounds__(256) void gcn_gemm(
    const float* __restrict__ x,        // [N, 128]
    const float* __restrict__ w,        // [128, 64]
    float* __restrict__ support)        // [N, 64]
{
    __shared__ float wl[D_IN * D_OUT];      // [k][col], 32 KB
    __shared__ float xT[32 * XT_STRIDE];    // [k_local][row], 33.3 KB

    const int t  = threadIdx.x;
    const int tx = t & 7;
    const int ty = t >> 3;
    const long row0 = (long)blockIdx.x * 256;

    {
        const float4* wf  = (const float4*)w;
        float4*       wlf = (float4*)wl;
#pragma unroll
        for (int j = 0; j < 8; ++j)
            wlf[t + 256 * j] = wf[t + 256 * j];
    }

    float acc[8][8];
#pragma unroll
    for (int i = 0; i < 8; ++i)
#pragma unroll
        for (int j = 0; j < 8; ++j)
            acc[i][j] = 0.f;

    for (int kc = 0; kc < 4; ++kc) {
        const int k0 = kc * 32;
        __syncthreads();

        const int kk = tx * 4;
#pragma unroll
        for (int it = 0; it < 8; ++it) {
            const int  rg   = it * 32 + ty;
            const long grow = row0 + rg;
            float4 v = make_float4(0.f, 0.f, 0.f, 0.f);
            if (grow < N_NODES)
                v = *(const float4*)&x[grow * D_IN + k0 + kk];
            xT[(kk + 0) * XT_STRIDE + rg] = v.x;
            xT[(kk + 1) * XT_STRIDE + rg] = v.y;
            xT[(kk + 2) * XT_STRIDE + rg] = v.z;
            xT[(kk + 3) * XT_STRIDE + rg] = v.w;
        }
        __syncthreads();

#pragma unroll 8
        for (int k = 0; k < 32; ++k) {
            const float4 a0 = *(const float4*)&xT[k * XT_STRIDE + ty * 8];
            const float4 a1 = *(const float4*)&xT[k * XT_STRIDE + ty * 8 + 4];
            const float4 b0 = *(const float4*)&wl[(k0 + k) * D_OUT + tx * 8];
            const float4 b1 = *(const float4*)&wl[(k0 + k) * D_OUT + tx * 8 + 4];
            const float av[8] = {a0.x, a0.y, a0.z, a0.w, a1.x, a1.y, a1.z, a1.w};
            const float bv[8] = {b0.x, b0.y, b0.z, b0.w, b1.x, b1.y, b1.z, b1.w};
#pragma unroll
            for (int i = 0; i < 8; ++i)
#pragma unroll
                for (int j = 0; j < 8; ++j)
                    acc[i][j] = fmaf(av[i], bv[j], acc[i][j]);
        }
    }

#pragma unroll
    for (int i = 0; i < 8; ++i) {
        const long r = row0 + ty * 8 + i;
        if (r < N_NODES) {
            float4 o0 = make_float4(acc[i][0], acc[i][1], acc[i][2], acc[i][3]);
            float4 o1 = make_float4(acc[i][4], acc[i][5], acc[i][6], acc[i][7]);
            *(float4*)&support[r * D_OUT + tx * 8]     = o0;
            *(float4*)&support[r * D_OUT + tx * 8 + 4] = o1;
        }
    }
}

// ---------------------------------------------------------------------------
// K1: per-(block,bucket) histogram. Block b counts its 6250-edge chunk into
// LDS, writes mat[b*NG+g] (contiguous, coalesced). No global memset needed.
// ---------------------------------------------------------------------------
__global__ __launch_bounds__(256) void k_count(
    const int* __restrict__ rows, int* __restrict__ mat)
{
    __shared__ int cnt[NG];
    const int t = threadIdx.x, b = blockIdx.x;
    for (int g = t; g < NG; g += 256) cnt[g] = 0;
    __syncthreads();
    const int base = b * CHUNK;
    for (int j = t; j < CHUNK; j += 256)
        atomicAdd(&cnt[rows[base + j] >> 7], 1);
    __syncthreads();
    for (int g = t; g < NG; g += 256) mat[b * NG + g] = cnt[g];
}

// ---------------------------------------------------------------------------
// K2: per-bucket exclusive scan over the 256 blocks (in place), totals out.
// grid = NG blocks, 256 threads (thread t = block index t).
// ---------------------------------------------------------------------------
__global__ __launch_bounds__(256) void k_scanb(
    int* __restrict__ mat, int* __restrict__ totals)
{
    __shared__ int s[NB];
    const int g = blockIdx.x, t = threadIdx.x;
    const int v = mat[t * NG + g];
    s[t] = v;
    __syncthreads();
#pragma unroll
    for (int off = 1; off < NB; off <<= 1) {
        const int add = (t >= off) ? s[t - off] : 0;
        __syncthreads();
        s[t] += add;
        __syncthreads();
    }
    mat[t * NG + g] = s[t] - v;          // exclusive within bucket
    if (t == NB - 1) totals[g] = s[t];
}

// ---------------------------------------------------------------------------
// K3: exclusive scan of bucket totals -> bstart[0..NG], sentinel at NG.
// ---------------------------------------------------------------------------
__global__ __launch_bounds__(1024) void k_scant(
    const int* __restrict__ totals, int* __restrict__ bstart)
{
    __shared__ int s[1024];
    const int t = threadIdx.x;
    const int v = (t < NG) ? totals[t] : 0;
    s[t] = v;
    __syncthreads();
#pragma unroll
    for (int off = 1; off < 1024; off <<= 1) {
        const int add = (t >= off) ? s[t - off] : 0;
        __syncthreads();
        s[t] += add;
        __syncthreads();
    }
    if (t < NG) bstart[t] = s[t] - v;
    if (t == NG - 1) bstart[NG] = s[t];  // sentinel = E
}

// ---------------------------------------------------------------------------
// K4: place. Block b re-reads its chunk; LDS cursors give each (b,g) an
// EXCLUSIVE contiguous output sub-range (~8 edges = one 64B line, single
// writer, dense in time) -> no partial-line writeback amplification.
// pack: val(32) | col(17)<<7 | row_local(7)
// ---------------------------------------------------------------------------
__global__ __launch_bounds__(256) void k_place(
    const int* __restrict__ rows, const int* __restrict__ cols,
    const float* __restrict__ vals, const int* __restrict__ mat,
    const int* __restrict__ bstart, ull* __restrict__ pairs)
{
    __shared__ int cursor[NG];
    const int t = threadIdx.x, b = blockIdx.x;
    for (int g = t; g < NG; g += 256)
        cursor[g] = bstart[g] + mat[b * NG + g];
    __syncthreads();
    const int base = b * CHUNK;
    for (int j = t; j < CHUNK; j += 256) {
        const int e = base + j;
        const int r = rows[e];
        const unsigned c = (unsigned)cols[e];
        const float v = vals[e];
        const int pos = atomicAdd(&cursor[r >> 7], 1);
        pairs[pos] = ((ull)__float_as_uint(v) << 32) | (c << 7) | (unsigned)(r & 127);
    }
}

// ---------------------------------------------------------------------------
// K5: bucket reduce + fused PReLU. One block per bucket; pairs are contiguous.
// Wave-uniform pair load, 64-lane support gather, ds_add_f32 into 32 KB LDS
// acc (lane=col -> 2 lanes/bank, conflict-free). Coalesced PReLU write-out.
// ---------------------------------------------------------------------------
__global__ __launch_bounds__(256) void k_accum(
    const ull* __restrict__ pairs, const int* __restrict__ bstart,
    const float* __restrict__ support, const float* __restrict__ prelu_a,
    float* __restrict__ out)
{
    __shared__ float acc[BROWS * D_OUT];   // 32 KB
    const int t = threadIdx.x, g = blockIdx.x;
    const int lane = t & 63, w = t >> 6;

    for (int i = t; i < BROWS * D_OUT; i += 256) acc[i] = 0.f;
    __syncthreads();

    const int start = bstart[g], end = bstart[g + 1];
    int e = start + w;
    for (; e + 4 < end; e += 8) {
        const ull p0 = pairs[e];
        const ull p1 = pairs[e + 4];
        const unsigned lo0 = (unsigned)p0, lo1 = (unsigned)p1;
        const float s0 = support[(size_t)(lo0 >> 7) * D_OUT + lane];
        const float s1 = support[(size_t)(lo1 >> 7) * D_OUT + lane];
        atomicAdd(&acc[(lo0 & 127) * D_OUT + lane],
                  __uint_as_float((unsigned)(p0 >> 32)) * s0);
        atomicAdd(&acc[(lo1 & 127) * D_OUT + lane],
                  __uint_as_float((unsigned)(p1 >> 32)) * s1);
    }
    for (; e < end; e += 4) {
        const ull p = pairs[e];
        const unsigned lo = (unsigned)p;
        const float s = support[(size_t)(lo >> 7) * D_OUT + lane];
        atomicAdd(&acc[(lo & 127) * D_OUT + lane],
                  __uint_as_float((unsigned)(p >> 32)) * s);
    }
    __syncthreads();

    const float a = prelu_a[0];
    for (int rl = w; rl < BROWS; rl += 4) {
        const int row = g * BROWS + rl;
        if (row < N_NODES) {
            const float v = acc[rl * D_OUT + lane];
            out[(size_t)row * D_OUT + lane] = v > 0.f ? v : a * v;
        }
    }
}

// ---------------------------------------------------------------------------
extern "C" void kernel_launch(void* const* d_in, const int* in_sizes, int n_in,
                              void* d_out, int out_size, void* d_ws, size_t ws_size,
                              hipStream_t stream) {
    const float* x    = (const float*)d_in[0];
    const int*   rows = (const int*)d_in[1];
    const int*   cols = (const int*)d_in[2];
    const float* vals = (const float*)d_in[3];
    const float* w    = (const float*)d_in[4];
    const float* pa   = (const float*)d_in[5];

    float* out     = (float*)d_out;                    // [N*64] PReLU output
    float* support = out + (size_t)N_NODES * D_OUT;    // [N*64] support (tuple elem 1)

    // workspace layout (~13.6 MB)
    ull* pairs  = (ull*)d_ws;                  // 1.6M x 8B
    int* mat    = (int*)(pairs + N_EDGES);     // NB*NG = 200192 ints
    int* totals = mat + NB * NG;               // 782 (pad 784)
    int* bstart = totals + 784;                // 783 (pad 784)

    gcn_gemm<<<(N_NODES + 255) / 256, 256, 0, stream>>>(x, w, support);
    k_count <<<NB, 256, 0, stream>>>(rows, mat);
    k_scanb <<<NG, 256, 0, stream>>>(mat, totals);
    k_scant <<<1, 1024, 0, stream>>>(totals, bstart);
    k_place <<<NB, 256, 0, stream>>>(rows, cols, vals, mat, bstart, pairs);
    k_accum <<<NG, 256, 0, stream>>>(pairs, bstart, support, pa, out);
}

// Round 7
// 762.946 us; speedup vs baseline: 1.1347x; 1.1347x over previous
//
#include <hip/hip_runtime.h>

#define N_NODES 100000
#define N_EDGES 1600000
#define D_IN    128
#define D_OUT   64

#define XT_STRIDE 260     // gemm xT padded stride
#define NB    256         // binning blocks
#define CHUNK 6250        // edges per binning block (256*6250 = 1.6M exact)
#define NG    3125        // buckets: row>>5, 100000/32 exact
#define BROWS 32          // rows per bucket
typedef unsigned long long ull;

// ---------------------------------------------------------------------------
// Kernel A: support = X @ W (fp32). Register-tiled LDS GEMM (unchanged).
// ---------------------------------------------------------------------------
__global__ __launch_bounds__(256) void gcn_gemm(
    const float* __restrict__ x,        // [N, 128]
    const float* __restrict__ w,        // [128, 64]
    float* __restrict__ support)        // [N, 64]
{
    __shared__ float wl[D_IN * D_OUT];      // [k][col], 32 KB
    __shared__ float xT[32 * XT_STRIDE];    // [k_local][row], 33.3 KB

    const int t  = threadIdx.x;
    const int tx = t & 7;
    const int ty = t >> 3;
    const long row0 = (long)blockIdx.x * 256;

    {
        const float4* wf  = (const float4*)w;
        float4*       wlf = (float4*)wl;
#pragma unroll
        for (int j = 0; j < 8; ++j)
            wlf[t + 256 * j] = wf[t + 256 * j];
    }

    float acc[8][8];
#pragma unroll
    for (int i = 0; i < 8; ++i)
#pragma unroll
        for (int j = 0; j < 8; ++j)
            acc[i][j] = 0.f;

    for (int kc = 0; kc < 4; ++kc) {
        const int k0 = kc * 32;
        __syncthreads();

        const int kk = tx * 4;
#pragma unroll
        for (int it = 0; it < 8; ++it) {
            const int  rg   = it * 32 + ty;
            const long grow = row0 + rg;
            float4 v = make_float4(0.f, 0.f, 0.f, 0.f);
            if (grow < N_NODES)
                v = *(const float4*)&x[grow * D_IN + k0 + kk];
            xT[(kk + 0) * XT_STRIDE + rg] = v.x;
            xT[(kk + 1) * XT_STRIDE + rg] = v.y;
            xT[(kk + 2) * XT_STRIDE + rg] = v.z;
            xT[(kk + 3) * XT_STRIDE + rg] = v.w;
        }
        __syncthreads();

#pragma unroll 8
        for (int k = 0; k < 32; ++k) {
            const float4 a0 = *(const float4*)&xT[k * XT_STRIDE + ty * 8];
            const float4 a1 = *(const float4*)&xT[k * XT_STRIDE + ty * 8 + 4];
            const float4 b0 = *(const float4*)&wl[(k0 + k) * D_OUT + tx * 8];
            const float4 b1 = *(const float4*)&wl[(k0 + k) * D_OUT + tx * 8 + 4];
            const float av[8] = {a0.x, a0.y, a0.z, a0.w, a1.x, a1.y, a1.z, a1.w};
            const float bv[8] = {b0.x, b0.y, b0.z, b0.w, b1.x, b1.y, b1.z, b1.w};
#pragma unroll
            for (int i = 0; i < 8; ++i)
#pragma unroll
                for (int j = 0; j < 8; ++j)
                    acc[i][j] = fmaf(av[i], bv[j], acc[i][j]);
        }
    }

#pragma unroll
    for (int i = 0; i < 8; ++i) {
        const long r = row0 + ty * 8 + i;
        if (r < N_NODES) {
            float4 o0 = make_float4(acc[i][0], acc[i][1], acc[i][2], acc[i][3]);
            float4 o1 = make_float4(acc[i][4], acc[i][5], acc[i][6], acc[i][7]);
            *(float4*)&support[r * D_OUT + tx * 8]     = o0;
            *(float4*)&support[r * D_OUT + tx * 8 + 4] = o1;
        }
    }
}

// ---------------------------------------------------------------------------
// K1: per-(block,bucket) histogram into LDS, write mat[b][g] coalesced.
// ---------------------------------------------------------------------------
__global__ __launch_bounds__(256) void k_count(
    const int* __restrict__ rows, int* __restrict__ mat)
{
    __shared__ int cnt[NG];                 // 12.5 KB
    const int t = threadIdx.x, b = blockIdx.x;
    for (int g = t; g < NG; g += 256) cnt[g] = 0;
    __syncthreads();
    const int base = b * CHUNK;
    for (int j = t; j < CHUNK; j += 256)
        atomicAdd(&cnt[rows[base + j] >> 5], 1);
    __syncthreads();
    for (int g = t; g < NG; g += 256) mat[b * NG + g] = cnt[g];
}

// ---------------------------------------------------------------------------
// K2: per-bucket exclusive scan over the 256 blocks (in place), totals out.
// grid = NG blocks; thread t = binning-block index t.
// ---------------------------------------------------------------------------
__global__ __launch_bounds__(256) void k_scanb(
    int* __restrict__ mat, int* __restrict__ totals)
{
    __shared__ int s[NB];
    const int g = blockIdx.x, t = threadIdx.x;
    const int v = mat[t * NG + g];
    s[t] = v;
    __syncthreads();
#pragma unroll
    for (int off = 1; off < NB; off <<= 1) {
        const int add = (t >= off) ? s[t - off] : 0;
        __syncthreads();
        s[t] += add;
        __syncthreads();
    }
    mat[t * NG + g] = s[t] - v;          // exclusive within bucket
    if (t == NB - 1) totals[g] = s[t];
}

// ---------------------------------------------------------------------------
// K3: exclusive scan of NG=3125 bucket totals -> bstart[0..NG] (sentinel=E).
// Single block of 1024, 4 chunks with running carry.
// ---------------------------------------------------------------------------
__global__ __launch_bounds__(1024) void k_scant(
    const int* __restrict__ totals, int* __restrict__ bstart)
{
    __shared__ int s[1024];
    __shared__ int carry;
    const int t = threadIdx.x;
    if (t == 0) carry = 0;
    __syncthreads();
    for (int c = 0; c < 4; ++c) {
        const int i = c * 1024 + t;
        const int v = (i < NG) ? totals[i] : 0;
        s[t] = v;
        __syncthreads();
#pragma unroll
        for (int off = 1; off < 1024; off <<= 1) {
            const int add = (t >= off) ? s[t - off] : 0;
            __syncthreads();
            s[t] += add;
            __syncthreads();
        }
        const int base = carry;          // uniform read (carry stable here)
        if (i < NG) bstart[i] = base + s[t] - v;
        __syncthreads();
        if (t == 1023) carry = base + s[1023];
        __syncthreads();
    }
    if (t == 0) bstart[NG] = carry;      // = E
}

// ---------------------------------------------------------------------------
// K4: place. Block b re-reads its chunk; LDS cursors give each (b,g) an
// exclusive contiguous output sub-range. pack: val(32) | col(17)<<5 | row5.
// ---------------------------------------------------------------------------
__global__ __launch_bounds__(256) void k_place(
    const int* __restrict__ rows, const int* __restrict__ cols,
    const float* __restrict__ vals, const int* __restrict__ mat,
    const int* __restrict__ bstart, ull* __restrict__ pairs)
{
    __shared__ int cursor[NG];              // 12.5 KB
    const int t = threadIdx.x, b = blockIdx.x;
    for (int g = t; g < NG; g += 256)
        cursor[g] = bstart[g] + mat[b * NG + g];
    __syncthreads();
    const int base = b * CHUNK;
    for (int j = t; j < CHUNK; j += 256) {
        const int e = base + j;
        const int r = rows[e];
        const unsigned c = (unsigned)cols[e];
        const float v = vals[e];
        const int pos = atomicAdd(&cursor[r >> 5], 1);
        pairs[pos] = ((ull)__float_as_uint(v) << 32) | (c << 5) | (unsigned)(r & 31);
    }
}

// ---------------------------------------------------------------------------
// K5: bucket reduce + fused PReLU. 3125 blocks (one per 32-row bucket).
// 4 waves/block, unroll-8 per wave -> up to 256 outstanding row-gathers/CU.
// 8 KB LDS accumulator; output writes fully contiguous (NG*BROWS == N).
// ---------------------------------------------------------------------------
__global__ __launch_bounds__(256) void k_accum(
    const ull* __restrict__ pairs, const int* __restrict__ bstart,
    const float* __restrict__ support, const float* __restrict__ prelu_a,
    float* __restrict__ out)
{
    __shared__ float acc[BROWS * D_OUT];    // 8 KB
    const int t = threadIdx.x, g = blockIdx.x;
    const int lane = t & 63, w = t >> 6;

    for (int i = t; i < BROWS * D_OUT; i += 256) acc[i] = 0.f;
    __syncthreads();

    const int start = bstart[g], end = bstart[g + 1];
    int e = start + w;
    for (; e + 28 < end; e += 32) {
        ull p[8];
#pragma unroll
        for (int u = 0; u < 8; ++u) p[u] = pairs[e + 4 * u];
        float s8[8];
#pragma unroll
        for (int u = 0; u < 8; ++u) {
            const unsigned lo = (unsigned)p[u];
            s8[u] = support[(size_t)(lo >> 5) * D_OUT + lane];
        }
#pragma unroll
        for (int u = 0; u < 8; ++u) {
            const unsigned lo = (unsigned)p[u];
            atomicAdd(&acc[(lo & 31) * D_OUT + lane],
                      __uint_as_float((unsigned)(p[u] >> 32)) * s8[u]);
        }
    }
    for (; e < end; e += 4) {
        const ull p = pairs[e];
        const unsigned lo = (unsigned)p;
        const float s = support[(size_t)(lo >> 5) * D_OUT + lane];
        atomicAdd(&acc[(lo & 31) * D_OUT + lane],
                  __uint_as_float((unsigned)(p >> 32)) * s);
    }
    __syncthreads();

    const float a = prelu_a[0];
    // out rows g*32..g*32+31 are contiguous: out[g*2048 + i], i = rl*64+col
    float* ob = out + (size_t)g * (BROWS * D_OUT);
    for (int i = t; i < BROWS * D_OUT; i += 256) {
        const float v = acc[i];
        ob[i] = v > 0.f ? v : a * v;
    }
}

// ---------------------------------------------------------------------------
extern "C" void kernel_launch(void* const* d_in, const int* in_sizes, int n_in,
                              void* d_out, int out_size, void* d_ws, size_t ws_size,
                              hipStream_t stream) {
    const float* x    = (const float*)d_in[0];
    const int*   rows = (const int*)d_in[1];
    const int*   cols = (const int*)d_in[2];
    const float* vals = (const float*)d_in[3];
    const float* w    = (const float*)d_in[4];
    const float* pa   = (const float*)d_in[5];

    float* out     = (float*)d_out;                    // [N*64] PReLU output
    float* support = out + (size_t)N_NODES * D_OUT;    // [N*64] support (tuple elem 1)

    // workspace layout (~16 MB)
    ull* pairs  = (ull*)d_ws;                  // 1.6M x 8B = 12.8 MB
    int* mat    = (int*)(pairs + N_EDGES);     // NB*NG = 800000 ints = 3.2 MB
    int* totals = mat + NB * NG;               // 3125 (pad 3128)
    int* bstart = totals + 3128;               // 3126

    gcn_gemm<<<(N_NODES + 255) / 256, 256, 0, stream>>>(x, w, support);
    k_count <<<NB, 256, 0, stream>>>(rows, mat);
    k_scanb <<<NG, 256, 0, stream>>>(mat, totals);
    k_scant <<<1, 1024, 0, stream>>>(totals, bstart);
    k_place <<<NB, 256, 0, stream>>>(rows, cols, vals, mat, bstart, pairs);
    k_accum <<<NG, 256, 0, stream>>>(pairs, bstart, support, pa, out);
}